// Round 1
// baseline (291.471 us; speedup 1.0000x reference)
//
#include <hip/hip_runtime.h>
#include <math.h>

// Problem geometry (fixed by setup_inputs)
#define NN 2
#define DD 160
#define HH 192
#define WW 160
#define DO 154   // DD-6
#define HO 186   // HH-6
#define WO 154   // WW-6
#define CS (NN*DD*HH*WO)   // per-channel elements in buf1 = 9,461,760

// Stage-B tiling
#define TX 64
#define TY 4
#define ZCHUNKS 4
#define ZC 39    // ceil(154/4)

__device__ __forceinline__ unsigned mono_f2u(float f) {
  unsigned u = __float_as_uint(f);
  return (u & 0x80000000u) ? ~u : (u | 0x80000000u);
}

__global__ void init_acc(float* acc) {
  acc[0] = 0.f;  // S_ncc_v
  acc[1] = 0.f;  // S_ncc
  acc[2] = 0.f;  // S_v
  acc[3] = 0.f;  // count
  ((unsigned*)acc)[4] = 0xFFFFFFFFu;  // vmin (monotone-uint encoding; max == +inf)
}

// Stage A: W-direction 7-tap box sums of the 5 moment channels.
// buf1 layout: [ch][n][z][h][wo], ch-planar, stride CS.
__global__ __launch_bounds__(256) void wfilt(const float* __restrict__ X,
                                             const float* __restrict__ Y,
                                             float* __restrict__ B1) {
  int idx = blockIdx.x * 256 + threadIdx.x;
  if (idx >= CS) return;
  int wo = idx % WO;
  int t  = idx / WO;
  int h  = t % HH;
  t /= HH;                  // t = n*DD + z
  const float* xr = X + ((size_t)t * HH + h) * WW + wo;
  const float* yr = Y + ((size_t)t * HH + h) * WW + wo;
  float sx = 0.f, sy = 0.f, sxx = 0.f, syy = 0.f, sxy = 0.f;
#pragma unroll
  for (int d = 0; d < 7; ++d) {
    float a = xr[d], b = yr[d];
    sx += a; sy += b; sxx += a * a; syy += b * b; sxy += a * b;
  }
  B1[idx]          = sx;
  B1[idx + CS]     = sy;
  B1[idx + 2*CS]   = sxx;
  B1[idx + 3*CS]   = syy;
  B1[idx + 4*CS]   = sxy;
}

__device__ float block_sum(float v, float* sm) {
  int tid = threadIdx.x;
  sm[tid] = v;
  __syncthreads();
#pragma unroll
  for (int off = 128; off > 0; off >>= 1) {
    if (tid < off) sm[tid] += sm[tid + off];
    __syncthreads();
  }
  float r = sm[0];
  __syncthreads();
  return r;
}

// Stage B: H 7-tap (direct loads) + D 7-tap (register ring buffer, unrolled x7),
// NCC per voxel, block-local reduction of {S_nv, S_n, S_v, cnt, vmin}.
__global__ __launch_bounds__(256) void hdncc(const float* __restrict__ B1,
                                             float* __restrict__ acc) {
  const int tx = threadIdx.x & 63;
  const int ty = threadIdx.x >> 6;
  const int wo = blockIdx.x * TX + tx;
  const int ho = blockIdx.y * TY + ty;
  const int n  = blockIdx.z >> 2;       // ZCHUNKS == 4
  const int ck = blockIdx.z & 3;
  const int zo0 = ck * ZC;
  const int zo1 = min(DO, zo0 + ZC);
  const bool act = (wo < WO) && (ho < HO);

  float rs0 = 0.f, rs1 = 0.f, rs2 = 0.f, rs3 = 0.f, rs4 = 0.f;
  float ring[5][7];
#pragma unroll
  for (int s = 0; s < 7; ++s) {
    ring[0][s] = 0.f; ring[1][s] = 0.f; ring[2][s] = 0.f;
    ring[3][s] = 0.f; ring[4][s] = 0.f;
  }

  float p_snv = 0.f, p_sn = 0.f, p_sv = 0.f, p_cnt = 0.f, p_vmin = 3.4e38f;

  if (act) {
    const float* base = B1 + (((size_t)n * DD + zo0) * HH + ho) * WO + wo;
    const int nz = zo1 - zo0 + 6;
    const float inv_nw = 1.0f / 343.0f;
    const float LO = -1.0f - 1e-5f, HI = 1.0f + 1e-5f;
    int i = 0;
    while (i < nz) {
#pragma unroll
      for (int s = 0; s < 7; ++s, ++i) {
        if (i < nz) {
          const float* p = base + (size_t)i * (HH * WO);
          float t0 = 0.f, t1 = 0.f, t2 = 0.f, t3 = 0.f, t4 = 0.f;
#pragma unroll
          for (int dh = 0; dh < 7; ++dh) {
            const float* q = p + dh * WO;
            t0 += q[0];
            t1 += q[CS];
            t2 += q[2*CS];
            t3 += q[3*CS];
            t4 += q[4*CS];
          }
          rs0 += t0 - ring[0][s]; ring[0][s] = t0;
          rs1 += t1 - ring[1][s]; ring[1][s] = t1;
          rs2 += t2 - ring[2][s]; ring[2][s] = t2;
          rs3 += t3 - ring[3][s]; ring[3][s] = t3;
          rs4 += t4 - ring[4][s]; ring[4][s] = t4;
          if (i >= 6) {
            float num = rs4 - rs0 * rs1 * inv_nw;
            float d0  = rs2 - rs0 * rs0 * inv_nw;
            float d1  = rs3 - rs1 * rs1 * inv_nw;
            float den = d0 * d1;
            if (den > 1e-5f) {
              float ncc = num / sqrtf(den);
              if (ncc >= LO && ncc <= HI) {
                float v = 0.5f * (d0 + d1);
                p_snv += ncc * v;
                p_sn  += ncc;
                p_sv  += v;
                p_cnt += 1.f;
                p_vmin = fminf(p_vmin, v);
              }
            }
          }
        }
      }
    }
  }

  __shared__ float sm[256];
  float bsnv = block_sum(p_snv, sm);
  float bsn  = block_sum(p_sn, sm);
  float bsv  = block_sum(p_sv, sm);
  float bcnt = block_sum(p_cnt, sm);
  // min reduce
  int tid = threadIdx.x;
  sm[tid] = p_vmin;
  __syncthreads();
#pragma unroll
  for (int off = 128; off > 0; off >>= 1) {
    if (tid < off) sm[tid] = fminf(sm[tid], sm[tid + off]);
    __syncthreads();
  }
  if (tid == 0) {
    atomicAdd(&acc[0], bsnv);
    atomicAdd(&acc[1], bsn);
    atomicAdd(&acc[2], bsv);
    atomicAdd(&acc[3], bcnt);
    atomicMin((unsigned*)acc + 4, mono_f2u(sm[0]));
  }
}

// Finalize: loss = 1 - (S_nv - vmin*S_n) / (S_v - vmin*cnt)
// (the min-max weight scale HIGH/(vmax-vmin+1e-12) cancels in w/sum(w))
__global__ void fin(const float* __restrict__ acc, float* __restrict__ out) {
  float snv = acc[0], sn = acc[1], sv = acc[2], cnt = acc[3];
  unsigned u = ((const unsigned*)acc)[4];
  unsigned bits = (u & 0x80000000u) ? (u ^ 0x80000000u) : ~u;
  float vmin = __uint_as_float(bits);
  float T = sv - vmin * cnt;
  float S = snv - vmin * sn;
  out[0] = 1.0f - S / T;
}

extern "C" void kernel_launch(void* const* d_in, const int* in_sizes, int n_in,
                              void* d_out, int out_size, void* d_ws, size_t ws_size,
                              hipStream_t stream) {
  const float* X = (const float*)d_in[0];  // y_pred
  const float* Y = (const float*)d_in[1];  // y_true
  // d_in[2] is the ones kernel (343 taps) — constant, unused.

  float* acc = (float*)d_ws;
  float* B1  = (float*)((char*)d_ws + 256);

  init_acc<<<1, 1, 0, stream>>>(acc);
  wfilt<<<(CS + 255) / 256, 256, 0, stream>>>(X, Y, B1);
  dim3 g((WO + TX - 1) / TX, (HO + TY - 1) / TY, NN * ZCHUNKS);
  hdncc<<<g, 256, 0, stream>>>(B1, acc);
  fin<<<1, 1, 0, stream>>>(acc, (float*)d_out);
}